// Round 3
// baseline (362.915 us; speedup 1.0000x reference)
//
#include <hip/hip_runtime.h>
#include <math.h>

// Problem constants (from reference)
#define NPTS   65536        // 256*256
#define NB     5
#define NX     25
#define NY     7
#define NZ     6
#define NW     5
#define FG     (NB*NX*NY*NZ*NW)       // 26250 f_grid elements
#define GRID_ELEMS (2000 * FG)        // 52,500,000
// Aligned-chunk decomposition: dst base (out+1+NPTS) is 4 mod 16 bytes, so
// elements e ≡ 3 (mod 4) start 16B-aligned dst chunks.
// edges: e = 0,1,2 and e = GRID_ELEMS-1; main chunks i cover e = 3+4i.
#define NCHUNKM ((GRID_ELEMS - 4) / 4)   // 13,124,999 aligned 16B chunks
// out layout: [0]=loss, [1 .. 65536]=theta[0], [65537 ..]=grid_new
// ws layout: [0..4]=s[n], [5]=sum|theta|, [6]=sum(f*W4)

typedef float float4a __attribute__((ext_vector_type(4), aligned(4)));
typedef float float4v __attribute__((ext_vector_type(4), aligned(16)));

__device__ __forceinline__ float fgrid_eval(const float* s, int e2, float* w4out) {
    const float PI2 = 6.283185307179586f;
    const float dxs = PI2 / 24.0f;
    const float dys = 0.03f;          // 0.18/6
    const float dzs = 0.036f;         // 0.18/5
    const float dws = 0.05f;          // 0.2/4
    int d  = e2 % NW;
    int cz = (e2 / NW) % NZ;
    int b  = (e2 / (NW * NZ)) % NY;
    int a  = (e2 / (NW * NZ * NY)) % NX;
    int n  = e2 / (NW * NZ * NY * NX);
    float xv = PI2 * (float)a / 24.0f;
    float cv = cosf(xv);
    float yv = -0.09f + dys * (float)b;
    float zv = -0.09f + dzs * (float)cz;
    float wv = 0.9f  + dws * (float)d;
    float arg = s[n] * cv * wv + yv + zv;
    float f = expf(-arg * arg);
    *w4out = dxs * ((a == 0 || a == NX - 1) ? 0.5f : 1.0f)
           * dys * ((b == 0 || b == NY - 1) ? 0.5f : 1.0f)
           * dzs * ((cz == 0 || cz == NZ - 1) ? 0.5f : 1.0f)
           * dws * ((d == 0 || d == NW - 1) ? 0.5f : 1.0f);
    return f;
}

// Kernel A: s[n] = sum_i x[n,i]*theta[i], ws[5] = sum|theta|, theta passthrough.
__global__ void reduce_kernel(const float* __restrict__ x,
                              const float* __restrict__ theta,
                              float* __restrict__ out_theta,
                              float* __restrict__ ws) {
    __shared__ float smem[4 * 6];
    int idx = blockIdx.x * blockDim.x + threadIdx.x;   // 0..65535
    float t = theta[idx];
    out_theta[idx] = t;

    float vals[6];
#pragma unroll
    for (int n = 0; n < 5; ++n) vals[n] = x[n * NPTS + idx] * t;
    vals[5] = fabsf(t);

    int lane = threadIdx.x & 63;
    int wave = threadIdx.x >> 6;
#pragma unroll
    for (int k = 0; k < 6; ++k) {
        float v = vals[k];
#pragma unroll
        for (int off = 32; off > 0; off >>= 1) v += __shfl_down(v, off, 64);
        if (lane == 0) smem[wave * 6 + k] = v;
    }
    __syncthreads();
    if (threadIdx.x < 6) {
        float acc = smem[threadIdx.x] + smem[6 + threadIdx.x] +
                    smem[12 + threadIdx.x] + smem[18 + threadIdx.x];
        atomicAdd(&ws[threadIdx.x], acc);
    }
}

// Kernel B: one aligned 16B-dst chunk per thread; slot-j chunks compute f_grid
// instead; wave-reduced loss partial -> atomicAdd(ws[6]).
__global__ void __launch_bounds__(256)
copy_fgrid_kernel(const float* __restrict__ grid,
                  float* __restrict__ out_grid,      // out + 1 + NPTS
                  const float* __restrict__ ws_in,
                  float* __restrict__ ws_out,
                  const int* __restrict__ jptr) {
    const int j = *jptr;
    const int jlo = j * FG;
    const int jhi = jlo + FG;

    float s[5];
#pragma unroll
    for (int n = 0; n < 5; ++n) s[n] = ws_in[n];

    float local = 0.0f;
    const long long t = (long long)blockIdx.x * blockDim.x + threadIdx.x;

    if (t < NCHUNKM) {
        const int e0 = 3 + 4 * (int)t;                // < 2^31, dst 16B-aligned
        float4a v = *(const float4a*)(grid + e0);     // src misaligned by 12B
        if (e0 + 3 >= jlo && e0 < jhi) {
#pragma unroll
            for (int q = 0; q < 4; ++q) {
                int e = e0 + q;
                if (e >= jlo && e < jhi) {
                    float w4;
                    float f = fgrid_eval(s, e - jlo, &w4);
                    v[q] = f;
                    local += f * w4;
                }
            }
        }
        float4v vv = {v[0], v[1], v[2], v[3]};
        __builtin_nontemporal_store(vv, (float4v*)(out_grid + e0));
    }

    if (t == 0) {
        // edge elements not covered by aligned chunks
        const int edges[4] = {0, 1, 2, GRID_ELEMS - 1};
#pragma unroll
        for (int k = 0; k < 4; ++k) {
            int e = edges[k];
            float val;
            if (e >= jlo && e < jhi) {
                float w4;
                val = fgrid_eval(s, e - jlo, &w4);
                local += val * w4;
            } else {
                val = grid[e];
            }
            out_grid[e] = val;
        }
    }

#pragma unroll
    for (int off = 32; off > 0; off >>= 1) local += __shfl_down(local, off, 64);
    if ((threadIdx.x & 63) == 0 && local != 0.0f) atomicAdd(&ws_out[6], local);
}

// Kernel C: finalize loss
__global__ void finalize_kernel(const float* __restrict__ ws,
                                float* __restrict__ out) {
    out[0] = ws[6] - 0.5f * ws[5];
}

extern "C" void kernel_launch(void* const* d_in, const int* in_sizes, int n_in,
                              void* d_out, int out_size, void* d_ws, size_t ws_size,
                              hipStream_t stream) {
    const float* x     = (const float*)d_in[0];   // [5,256,256]
    const float* theta = (const float*)d_in[1];   // [1,256,256]
    const float* grid  = (const float*)d_in[2];   // [2000,5,25,7,6,5]
    const int*   jptr  = (const int*)d_in[3];     // scalar

    float* out = (float*)d_out;
    float* ws  = (float*)d_ws;

    hipMemsetAsync(ws, 0, 7 * sizeof(float), stream);

    reduce_kernel<<<NPTS / 256, 256, 0, stream>>>(x, theta, out + 1, ws);

    const int nblk = (NCHUNKM + 255) / 256;       // 51270
    copy_fgrid_kernel<<<nblk, 256, 0, stream>>>(grid, out + 1 + NPTS,
                                                ws, ws, jptr);

    finalize_kernel<<<1, 1, 0, stream>>>(ws, out);
}